// Round 16
// baseline (29.159 us; speedup 1.0000x reference)
//
#include <hip/hip_runtime.h>
#include <stdint.h>

#define NB 4096
#define QLEN 1024
#define NL 64
#define KLEN 32
#define NS (QLEN - KLEN + 1)   // 993
#define WSLICE 1856            // u32 per wave LDS slice

typedef __attribute__((ext_vector_type(8))) _Float16 half8;
typedef __attribute__((ext_vector_type(4))) float f32x4;

union fragh { uint32_t u[4]; half8 v; };

static __device__ __forceinline__ uint32_t pkh(float a, float b) {
    return __builtin_bit_cast(uint32_t, __builtin_amdgcn_cvt_pkrtz(a, b)); // v_cvt_pkrtz_f16_f32
}
static __device__ __forceinline__ float lo16f(uint32_t w) {
    return (float)__builtin_bit_cast(_Float16, (unsigned short)(w & 0xFFFFu));
}
static __device__ __forceinline__ float hi16f(uint32_t w) {
    return (float)__builtin_bit_cast(_Float16, (unsigned short)(w >> 16));
}
static __device__ __forceinline__ uint32_t pkh_rne(float a, float b) {  // RNE f16 pair
    unsigned short ha = __builtin_bit_cast(unsigned short, (_Float16)a);
    unsigned short hb = __builtin_bit_cast(unsigned short, (_Float16)b);
    return (uint32_t)ha | ((uint32_t)hb << 16);
}

__global__ __launch_bounds__(256, 4) void shapelet_r16(
    const float* __restrict__ ts,        // [B, Q]
    const float* __restrict__ shapelets, // [L, K]
    const float* __restrict__ fc_w,      // [2, L]
    const float* __restrict__ fc_b,      // [2]
    float* __restrict__ out)             // [B, 2]
{
    // 4 private slices, one per wave; NO __syncthreads in this kernel.
    __shared__ __align__(16) uint32_t lds[4 * WSLICE];   // 29.7 KB

    const int tid  = threadIdx.x;
    const int wave = tid >> 6;
    const int lane = tid & 63;
    const int col  = lane & 15;
    const int kg   = lane >> 4;
    const int row  = blockIdx.x * 4 + wave;   // this wave's batch row

    uint32_t* pkE = lds + wave * WSLICE;                   // [528]
    uint32_t* pkO = pkE + 528;                             // [528]
    uint32_t* nwh = pkO + 528;                             // [512]
    float*    s4  = reinterpret_cast<float*>(nwh + 512);   // [264]

    // --- pass 1: wave loads its whole row (4 float4/lane), packs, partials ---
    const float* rowp = ts + (size_t)row * QLEN;
    float4 v[4];
    #pragma unroll
    for (int c = 0; c < 4; ++c)
        v[c] = reinterpret_cast<const float4*>(rowp)[64 * c + lane];
    float x4[4];
    #pragma unroll
    for (int c = 0; c < 4; ++c) {
        const int p = 256 * c + 4 * lane + 4;
        x4[c] = (p < QLEN) ? rowp[p] : 0.0f;
    }
    #pragma unroll
    for (int c = 0; c < 4; ++c) {
        uint2 pe = { pkh(v[c].x, v[c].y), pkh(v[c].z, v[c].w) };
        uint2 po = { pkh(v[c].y, v[c].z), pkh(v[c].w, x4[c]) };
        reinterpret_cast<uint2*>(pkE)[64 * c + lane] = pe;
        reinterpret_cast<uint2*>(pkO)[64 * c + lane] = po;
        s4[64 * c + lane] =
            fmaf(v[c].x, v[c].x, fmaf(v[c].y, v[c].y, fmaf(v[c].z, v[c].z, v[c].w * v[c].w)));
    }
    if (lane < 16) { pkE[512 + lane] = 0u; pkO[512 + lane] = 0u; }
    if (lane < 8)  s4[256 + lane] = 0.0f;

    // --- B fragments (fp16 RTZ) + exact fp32 ssq partials ---
    fragh Bh[4];
    float ssq[4];
    #pragma unroll
    for (int lt = 0; lt < 4; ++lt) {
        const float* sp = shapelets + (lt * 16 + col) * KLEN + kg * 8;
        float4 f0 = *reinterpret_cast<const float4*>(sp);
        float4 f1 = *reinterpret_cast<const float4*>(sp + 4);
        Bh[lt].u[0] = pkh(f0.x, f0.y);
        Bh[lt].u[1] = pkh(f0.z, f0.w);
        Bh[lt].u[2] = pkh(f1.x, f1.y);
        Bh[lt].u[3] = pkh(f1.z, f1.w);
        float s = f0.x * f0.x;
        s = fmaf(f0.y, f0.y, s); s = fmaf(f0.z, f0.z, s); s = fmaf(f0.w, f0.w, s);
        s = fmaf(f1.x, f1.x, s); s = fmaf(f1.y, f1.y, s);
        s = fmaf(f1.z, f1.z, s); s = fmaf(f1.w, f1.w, s);
        ssq[lt] = s;   // kg-partial; reduced in epilogue
    }

    __builtin_amdgcn_wave_barrier();   // order pass-1 LDS writes before pass-2 reads

    // --- pass 2: win_sq from s4 partials + f16 sliding corrections -> nwh ---
    #pragma unroll
    for (int c = 0; c < 4; ++c) {
        const int q = 64 * c + lane;
        float s_[8];
        #pragma unroll
        for (int j = 0; j < 8; ++j) s_[j] = s4[q + j];
        float w0 = ((s_[0] + s_[1]) + (s_[2] + s_[3])) + ((s_[4] + s_[5]) + (s_[6] + s_[7]));
        uint32_t cw0 = pkE[2 * (q + 8)];
        uint32_t cw1 = pkE[2 * (q + 8) + 1];
        float x32 = lo16f(cw0), x33 = hi16f(cw0), x34 = lo16f(cw1);
        float w1 = fmaf(x32, x32, fmaf(-v[c].x, v[c].x, w0));
        float w2 = fmaf(x33, x33, fmaf(-v[c].y, v[c].y, w1));
        float w3 = fmaf(x34, x34, fmaf(-v[c].z, v[c].z, w2));
        const int p0 = 4 * q;
        float c0 = (p0 + 0 < NS) ? -0.5f * w0 : -60000.0f;
        float c1 = (p0 + 1 < NS) ? -0.5f * w1 : -60000.0f;
        float c2 = (p0 + 2 < NS) ? -0.5f * w2 : -60000.0f;
        float c3 = (p0 + 3 < NS) ? -0.5f * w3 : -60000.0f;
        const int qq = p0 & 31;
        const int W = ((p0 >> 5) << 4) + (((qq & 15) >> 2) << 2) + ((qq >> 4) << 1);
        uint2 hw = { pkh_rne(c0, c1), pkh_rne(c2, c3) };
        *reinterpret_cast<uint2*>(&nwh[W]) = hw;
    }

    __builtin_amdgcn_wave_barrier();   // order pass-2 stores before main-loop reads

    // --- main loop: 16 bodies x 2 tile-pairs; loads+cvts at body top,
    //     MFMA cluster wrapped in s_setprio(1)/(0)  [T5: independent waves] ---
    float rmax[4][4];
    #pragma unroll
    for (int lt = 0; lt < 4; ++lt)
        #pragma unroll
        for (int e = 0; e < 4; ++e) rmax[lt][e] = -3.0e38f;

    const int par = col & 1;
    const uint32_t* apk = (par ? pkO : pkE) + (((col - par) >> 1) + kg * 4);
    const int nwb = 4 * kg;

    #pragma unroll 1
    for (int p = 0; p < 16; ++p) {
        const uint32_t* ap0 = apk + 32 * p;
        const uint32_t* ap1 = apk + 32 * p + 16;

        // -- all 6 LDS reads --
        fragh Aa0, Ab0, Aa1, Ab1;
        #pragma unroll
        for (int j = 0; j < 4; ++j) Aa0.u[j] = ap0[j];
        #pragma unroll
        for (int j = 0; j < 4; ++j) Ab0.u[j] = ap0[8 + j];
        #pragma unroll
        for (int j = 0; j < 4; ++j) Aa1.u[j] = ap1[j];
        #pragma unroll
        for (int j = 0; j < 4; ++j) Ab1.u[j] = ap1[8 + j];
        uint4 nw0 = *reinterpret_cast<const uint4*>(&nwh[32 * p + nwb]);
        uint4 nw1 = *reinterpret_cast<const uint4*>(&nwh[32 * p + 16 + nwb]);

        // -- all 16 cvts --
        f32x4 ia0, ib0, ia1, ib1;
        ia0[0] = lo16f(nw0.x); ia0[1] = hi16f(nw0.x);
        ia0[2] = lo16f(nw0.y); ia0[3] = hi16f(nw0.y);
        ib0[0] = lo16f(nw0.z); ib0[1] = hi16f(nw0.z);
        ib0[2] = lo16f(nw0.w); ib0[3] = hi16f(nw0.w);
        ia1[0] = lo16f(nw1.x); ia1[1] = hi16f(nw1.x);
        ia1[2] = lo16f(nw1.y); ia1[3] = hi16f(nw1.y);
        ib1[0] = lo16f(nw1.z); ib1[1] = hi16f(nw1.z);
        ib1[2] = lo16f(nw1.w); ib1[3] = hi16f(nw1.w);

        // -- 16 MFMAs (priority-boosted) + 32 max3 --
        __builtin_amdgcn_s_setprio(1);
        f32x4 aa0[4], ab0[4], aa1[4], ab1[4];
        #pragma unroll
        for (int lt = 0; lt < 4; ++lt) {
            aa0[lt] = __builtin_amdgcn_mfma_f32_16x16x32_f16(Aa0.v, Bh[lt].v, ia0, 0, 0, 0);
            ab0[lt] = __builtin_amdgcn_mfma_f32_16x16x32_f16(Ab0.v, Bh[lt].v, ib0, 0, 0, 0);
            aa1[lt] = __builtin_amdgcn_mfma_f32_16x16x32_f16(Aa1.v, Bh[lt].v, ia1, 0, 0, 0);
            ab1[lt] = __builtin_amdgcn_mfma_f32_16x16x32_f16(Ab1.v, Bh[lt].v, ib1, 0, 0, 0);
        }
        __builtin_amdgcn_s_setprio(0);
        #pragma unroll
        for (int lt = 0; lt < 4; ++lt) {
            #pragma unroll
            for (int e = 0; e < 4; ++e) {
                rmax[lt][e] = fmaxf(fmaxf(aa0[lt][e], ab0[lt][e]), rmax[lt][e]);  // v_max3_f32
                rmax[lt][e] = fmaxf(fmaxf(aa1[lt][e], ab1[lt][e]), rmax[lt][e]);  // v_max3_f32
            }
        }
    }

    // --- epilogue: all in-wave shuffles, no LDS, no barrier ---
    float p0v = 0.0f, p1v = 0.0f;
    #pragma unroll
    for (int lt = 0; lt < 4; ++lt) {
        float m = fmaxf(fmaxf(rmax[lt][0], rmax[lt][1]),
                        fmaxf(rmax[lt][2], rmax[lt][3]));
        m = fmaxf(m, __shfl_xor(m, 16, 64));
        m = fmaxf(m, __shfl_xor(m, 32, 64));
        float sq = ssq[lt];
        sq += __shfl_xor(sq, 16, 64);
        sq += __shfl_xor(sq, 32, 64);
        float f = (sq - 2.0f * m) * (1.0f / (float)KLEN);   // min dist
        p0v = fmaf(f, fc_w[lt * 16 + col], p0v);
        p1v = fmaf(f, fc_w[NL + lt * 16 + col], p1v);
    }
    #pragma unroll
    for (int off = 1; off <= 8; off <<= 1) {
        p0v += __shfl_xor(p0v, off, 64);
        p1v += __shfl_xor(p1v, off, 64);
    }
    if (lane == 0) {
        out[(size_t)row * 2 + 0] = p0v + fc_b[0];
        out[(size_t)row * 2 + 1] = p1v + fc_b[1];
    }
}

extern "C" void kernel_launch(void* const* d_in, const int* in_sizes, int n_in,
                              void* d_out, int out_size, void* d_ws, size_t ws_size,
                              hipStream_t stream) {
    const float* ts        = (const float*)d_in[0];
    const float* shapelets = (const float*)d_in[1];
    const float* fc_w      = (const float*)d_in[2];
    const float* fc_b      = (const float*)d_in[3];
    float* out = (float*)d_out;

    shapelet_r16<<<NB / 4, 256, 0, stream>>>(ts, shapelets, fc_w, fc_b, out);
}

// Round 17
// 23.492 us; speedup vs baseline: 1.2412x; 1.2412x over previous
//
#include <hip/hip_runtime.h>
#include <stdint.h>

#define NB 4096
#define QLEN 1024
#define NL 64
#define KLEN 32
#define NS (QLEN - KLEN + 1)   // 993
#define WSLICE 1856            // u32 per wave LDS slice

typedef __attribute__((ext_vector_type(8))) _Float16 half8;
typedef __attribute__((ext_vector_type(4))) float f32x4;

union fragh { uint32_t u[4]; half8 v; };

static __device__ __forceinline__ uint32_t pkh(float a, float b) {
    return __builtin_bit_cast(uint32_t, __builtin_amdgcn_cvt_pkrtz(a, b)); // v_cvt_pkrtz_f16_f32
}
static __device__ __forceinline__ float lo16f(uint32_t w) {
    return (float)__builtin_bit_cast(_Float16, (unsigned short)(w & 0xFFFFu));
}
static __device__ __forceinline__ float hi16f(uint32_t w) {
    return (float)__builtin_bit_cast(_Float16, (unsigned short)(w >> 16));
}
static __device__ __forceinline__ uint32_t pkh_rne(float a, float b) {  // RNE f16 pair
    unsigned short ha = __builtin_bit_cast(unsigned short, (_Float16)a);
    unsigned short hb = __builtin_bit_cast(unsigned short, (_Float16)b);
    return (uint32_t)ha | ((uint32_t)hb << 16);
}

__global__ __launch_bounds__(256, 4) void shapelet_r17(
    const float* __restrict__ ts,        // [B, Q]
    const float* __restrict__ shapelets, // [L, K]
    const float* __restrict__ fc_w,      // [2, L]
    const float* __restrict__ fc_b,      // [2]
    float* __restrict__ out)             // [B, 2]
{
    // 4 private slices, one per wave; NO __syncthreads in this kernel.
    __shared__ __align__(16) uint32_t lds[4 * WSLICE];   // 29.7 KB

    const int tid  = threadIdx.x;
    const int wave = tid >> 6;
    const int lane = tid & 63;
    const int col  = lane & 15;
    const int kg   = lane >> 4;
    const int row  = blockIdx.x * 4 + wave;   // this wave's batch row

    uint32_t* pkE = lds + wave * WSLICE;                   // [528]
    uint32_t* pkO = pkE + 528;                             // [528]
    uint32_t* nwh = pkO + 528;                             // [512]
    float*    s4  = reinterpret_cast<float*>(nwh + 512);   // [264]

    // --- pass 1: wave loads its whole row (4 float4/lane), packs, partials ---
    const float* rowp = ts + (size_t)row * QLEN;
    float4 v[4];
    #pragma unroll
    for (int c = 0; c < 4; ++c)
        v[c] = reinterpret_cast<const float4*>(rowp)[64 * c + lane];
    float x4[4];
    #pragma unroll
    for (int c = 0; c < 4; ++c) {
        const int p = 256 * c + 4 * lane + 4;
        x4[c] = (p < QLEN) ? rowp[p] : 0.0f;
    }
    #pragma unroll
    for (int c = 0; c < 4; ++c) {
        uint2 pe = { pkh(v[c].x, v[c].y), pkh(v[c].z, v[c].w) };
        uint2 po = { pkh(v[c].y, v[c].z), pkh(v[c].w, x4[c]) };
        reinterpret_cast<uint2*>(pkE)[64 * c + lane] = pe;
        reinterpret_cast<uint2*>(pkO)[64 * c + lane] = po;
        s4[64 * c + lane] =
            fmaf(v[c].x, v[c].x, fmaf(v[c].y, v[c].y, fmaf(v[c].z, v[c].z, v[c].w * v[c].w)));
    }
    if (lane < 16) { pkE[512 + lane] = 0u; pkO[512 + lane] = 0u; }
    if (lane < 8)  s4[256 + lane] = 0.0f;

    // --- B fragments (fp16 RTZ) + exact fp32 ssq partials ---
    fragh Bh[4];
    float ssq[4];
    #pragma unroll
    for (int lt = 0; lt < 4; ++lt) {
        const float* sp = shapelets + (lt * 16 + col) * KLEN + kg * 8;
        float4 f0 = *reinterpret_cast<const float4*>(sp);
        float4 f1 = *reinterpret_cast<const float4*>(sp + 4);
        Bh[lt].u[0] = pkh(f0.x, f0.y);
        Bh[lt].u[1] = pkh(f0.z, f0.w);
        Bh[lt].u[2] = pkh(f1.x, f1.y);
        Bh[lt].u[3] = pkh(f1.z, f1.w);
        float s = f0.x * f0.x;
        s = fmaf(f0.y, f0.y, s); s = fmaf(f0.z, f0.z, s); s = fmaf(f0.w, f0.w, s);
        s = fmaf(f1.x, f1.x, s); s = fmaf(f1.y, f1.y, s);
        s = fmaf(f1.z, f1.z, s); s = fmaf(f1.w, f1.w, s);
        ssq[lt] = s;   // kg-partial; reduced in epilogue
    }

    __builtin_amdgcn_wave_barrier();   // order pass-1 LDS writes before pass-2 reads

    // --- pass 2: win_sq from s4 partials + f16 sliding corrections -> nwh ---
    #pragma unroll
    for (int c = 0; c < 4; ++c) {
        const int q = 64 * c + lane;
        float s_[8];
        #pragma unroll
        for (int j = 0; j < 8; ++j) s_[j] = s4[q + j];
        float w0 = ((s_[0] + s_[1]) + (s_[2] + s_[3])) + ((s_[4] + s_[5]) + (s_[6] + s_[7]));
        uint32_t cw0 = pkE[2 * (q + 8)];
        uint32_t cw1 = pkE[2 * (q + 8) + 1];
        float x32 = lo16f(cw0), x33 = hi16f(cw0), x34 = lo16f(cw1);
        float w1 = fmaf(x32, x32, fmaf(-v[c].x, v[c].x, w0));
        float w2 = fmaf(x33, x33, fmaf(-v[c].y, v[c].y, w1));
        float w3 = fmaf(x34, x34, fmaf(-v[c].z, v[c].z, w2));
        const int p0 = 4 * q;
        float c0 = (p0 + 0 < NS) ? -0.5f * w0 : -60000.0f;
        float c1 = (p0 + 1 < NS) ? -0.5f * w1 : -60000.0f;
        float c2 = (p0 + 2 < NS) ? -0.5f * w2 : -60000.0f;
        float c3 = (p0 + 3 < NS) ? -0.5f * w3 : -60000.0f;
        const int qq = p0 & 31;
        const int W = ((p0 >> 5) << 4) + (((qq & 15) >> 2) << 2) + ((qq >> 4) << 1);
        uint2 hw = { pkh_rne(c0, c1), pkh_rne(c2, c3) };
        *reinterpret_cast<uint2*>(&nwh[W]) = hw;
    }

    __builtin_amdgcn_wave_barrier();   // order pass-2 stores before main-loop reads

    // --- main loop: 16 bodies x 2 tile-pairs (r15's exact body), with
    //     (a) per-wave body rotation to break the 4-wave convoy,
    //     (b) setprio(1) around the interleaved MFMA+max3 cluster [T5]. ---
    float rmax[4][4];
    #pragma unroll
    for (int lt = 0; lt < 4; ++lt)
        #pragma unroll
        for (int e = 0; e < 4; ++e) rmax[lt][e] = -3.0e38f;

    const int par = col & 1;
    const uint32_t* apk = (par ? pkO : pkE) + (((col - par) >> 1) + kg * 4);
    const int nwb = 4 * kg;
    const int rot = wave * 4;            // stagger: wave w starts at body 4w

    #pragma unroll 1
    for (int pp = 0; pp < 16; ++pp) {
        const int p = (pp + rot) & 15;
        const uint32_t* ap0 = apk + 32 * p;
        const uint32_t* ap1 = apk + 32 * p + 16;

        // -- all 6 LDS reads --
        fragh Aa0, Ab0, Aa1, Ab1;
        #pragma unroll
        for (int j = 0; j < 4; ++j) Aa0.u[j] = ap0[j];
        #pragma unroll
        for (int j = 0; j < 4; ++j) Ab0.u[j] = ap0[8 + j];
        #pragma unroll
        for (int j = 0; j < 4; ++j) Aa1.u[j] = ap1[j];
        #pragma unroll
        for (int j = 0; j < 4; ++j) Ab1.u[j] = ap1[8 + j];
        uint4 nw0 = *reinterpret_cast<const uint4*>(&nwh[32 * p + nwb]);
        uint4 nw1 = *reinterpret_cast<const uint4*>(&nwh[32 * p + 16 + nwb]);

        // -- all 16 cvts --
        f32x4 ia0, ib0, ia1, ib1;
        ia0[0] = lo16f(nw0.x); ia0[1] = hi16f(nw0.x);
        ia0[2] = lo16f(nw0.y); ia0[3] = hi16f(nw0.y);
        ib0[0] = lo16f(nw0.z); ib0[1] = hi16f(nw0.z);
        ib0[2] = lo16f(nw0.w); ib0[3] = hi16f(nw0.w);
        ia1[0] = lo16f(nw1.x); ia1[1] = hi16f(nw1.x);
        ia1[2] = lo16f(nw1.y); ia1[3] = hi16f(nw1.y);
        ib1[0] = lo16f(nw1.z); ib1[1] = hi16f(nw1.z);
        ib1[2] = lo16f(nw1.w); ib1[3] = hi16f(nw1.w);

        // -- 16 MFMAs + 32 max3, interleaved per-lt exactly as r15 --
        __builtin_amdgcn_s_setprio(1);
        #pragma unroll
        for (int lt = 0; lt < 4; ++lt) {
            f32x4 aa0 = __builtin_amdgcn_mfma_f32_16x16x32_f16(Aa0.v, Bh[lt].v, ia0, 0, 0, 0);
            f32x4 ab0 = __builtin_amdgcn_mfma_f32_16x16x32_f16(Ab0.v, Bh[lt].v, ib0, 0, 0, 0);
            f32x4 aa1 = __builtin_amdgcn_mfma_f32_16x16x32_f16(Aa1.v, Bh[lt].v, ia1, 0, 0, 0);
            f32x4 ab1 = __builtin_amdgcn_mfma_f32_16x16x32_f16(Ab1.v, Bh[lt].v, ib1, 0, 0, 0);
            #pragma unroll
            for (int e = 0; e < 4; ++e) {
                rmax[lt][e] = fmaxf(fmaxf(aa0[e], ab0[e]), rmax[lt][e]);  // v_max3_f32
                rmax[lt][e] = fmaxf(fmaxf(aa1[e], ab1[e]), rmax[lt][e]);  // v_max3_f32
            }
        }
        __builtin_amdgcn_s_setprio(0);
    }

    // --- epilogue: all in-wave shuffles, no LDS, no barrier ---
    float p0v = 0.0f, p1v = 0.0f;
    #pragma unroll
    for (int lt = 0; lt < 4; ++lt) {
        float m = fmaxf(fmaxf(rmax[lt][0], rmax[lt][1]),
                        fmaxf(rmax[lt][2], rmax[lt][3]));
        m = fmaxf(m, __shfl_xor(m, 16, 64));
        m = fmaxf(m, __shfl_xor(m, 32, 64));
        float sq = ssq[lt];
        sq += __shfl_xor(sq, 16, 64);
        sq += __shfl_xor(sq, 32, 64);
        float f = (sq - 2.0f * m) * (1.0f / (float)KLEN);   // min dist
        p0v = fmaf(f, fc_w[lt * 16 + col], p0v);
        p1v = fmaf(f, fc_w[NL + lt * 16 + col], p1v);
    }
    #pragma unroll
    for (int off = 1; off <= 8; off <<= 1) {
        p0v += __shfl_xor(p0v, off, 64);
        p1v += __shfl_xor(p1v, off, 64);
    }
    if (lane == 0) {
        out[(size_t)row * 2 + 0] = p0v + fc_b[0];
        out[(size_t)row * 2 + 1] = p1v + fc_b[1];
    }
}

extern "C" void kernel_launch(void* const* d_in, const int* in_sizes, int n_in,
                              void* d_out, int out_size, void* d_ws, size_t ws_size,
                              hipStream_t stream) {
    const float* ts        = (const float*)d_in[0];
    const float* shapelets = (const float*)d_in[1];
    const float* fc_w      = (const float*)d_in[2];
    const float* fc_b      = (const float*)d_in[3];
    float* out = (float*)d_out;

    shapelet_r17<<<NB / 4, 256, 0, stream>>>(ts, shapelets, fc_w, fc_b, out);
}

// Round 19
// 23.452 us; speedup vs baseline: 1.2433x; 1.0017x over previous
//
#include <hip/hip_runtime.h>
#include <stdint.h>

#define NB 4096
#define QLEN 1024
#define NL 64
#define KLEN 32
#define NS (QLEN - KLEN + 1)   // 993

// per-block (1 wave = 1 row) LDS layout, u32 offsets. 8 pair-shifted copies
// (parity E/O x shift r=0..3), stride 528 so tail zeros (to index 527) fit.
// Reads go up to index 523; underflow writes (index -r) land in the previous
// array's 524..527 slack, which is never read as data.
#define ASTRIDE  528
#define OFF_E0   0
#define OFF_O0   (4 * ASTRIDE)          // 2112
#define OFF_NWH  (8 * ASTRIDE)          // 4224
#define OFF_S4   (OFF_NWH + 512)        // 4736
#define SLICE_SZ (OFF_S4 + 264)         // 5000 u32 = 20.0 KB -> 8 blocks/CU

typedef __attribute__((ext_vector_type(8))) _Float16 half8;
typedef __attribute__((ext_vector_type(4))) float f32x4;

union frag4 { uint4 q; half8 v; uint32_t u[4]; };

static __device__ __forceinline__ uint32_t pkh(float a, float b) {
    return __builtin_bit_cast(uint32_t, __builtin_amdgcn_cvt_pkrtz(a, b)); // v_cvt_pkrtz_f16_f32
}
static __device__ __forceinline__ float lo16f(uint32_t w) {
    return (float)__builtin_bit_cast(_Float16, (unsigned short)(w & 0xFFFFu));
}
static __device__ __forceinline__ float hi16f(uint32_t w) {
    return (float)__builtin_bit_cast(_Float16, (unsigned short)(w >> 16));
}
static __device__ __forceinline__ uint32_t pkh_rne(float a, float b) {  // RNE f16 pair
    unsigned short ha = __builtin_bit_cast(unsigned short, (_Float16)a);
    unsigned short hb = __builtin_bit_cast(unsigned short, (_Float16)b);
    return (uint32_t)ha | ((uint32_t)hb << 16);
}

__global__ __launch_bounds__(64, 2) void shapelet_r19(
    const float* __restrict__ ts,        // [B, Q]
    const float* __restrict__ shapelets, // [L, K]
    const float* __restrict__ fc_w,      // [2, L]
    const float* __restrict__ fc_b,      // [2]
    float* __restrict__ out)             // [B, 2]
{
    __shared__ __align__(16) uint32_t lds[SLICE_SZ];

    const int lane = threadIdx.x & 63;
    const int col  = lane & 15;
    const int kg   = lane >> 4;
    const int row  = blockIdx.x;

    uint32_t* E0 = lds + OFF_E0;
    uint32_t* E1 = E0 + ASTRIDE;
    uint32_t* E2 = E1 + ASTRIDE;
    uint32_t* E3 = E2 + ASTRIDE;
    uint32_t* O0 = lds + OFF_O0;
    uint32_t* O1 = O0 + ASTRIDE;
    uint32_t* O2 = O1 + ASTRIDE;
    uint32_t* O3 = O2 + ASTRIDE;
    uint32_t* nwh = lds + OFF_NWH;                          // [512] -0.5*win f16 pairs
    float*    s4  = reinterpret_cast<float*>(lds + OFF_S4); // [264]

    // --- pass 1: load row, pack f16 pairs into 8 shifted arrays, s4 partials ---
    const float* rowp = ts + (size_t)row * QLEN;
    float4 v[4];
    float  x4[4];
    #pragma unroll
    for (int c = 0; c < 4; ++c)
        v[c] = reinterpret_cast<const float4*>(rowp)[64 * c + lane];
    #pragma unroll
    for (int c = 0; c < 4; ++c) {
        const int p = 256 * c + 4 * lane + 4;
        x4[c] = (p < QLEN) ? rowp[p] : 0.0f;
    }
    #pragma unroll
    for (int c = 0; c < 4; ++c) {
        const int P = 128 * c + 2 * lane;    // even pair index; pe covers pairs P, P+1
        uint2 pe = { pkh(v[c].x, v[c].y), pkh(v[c].z, v[c].w) };
        uint2 po = { pkh(v[c].y, v[c].z), pkh(v[c].w, x4[c]) };
        *reinterpret_cast<uint2*>(E0 + P) = pe;
        E1[P - 1] = pe.x; E1[P] = pe.y;
        *reinterpret_cast<uint2*>(E2 + P - 2) = pe;
        E3[P - 3] = pe.x; E3[P - 2] = pe.y;
        *reinterpret_cast<uint2*>(O0 + P) = po;
        O1[P - 1] = po.x; O1[P] = po.y;
        *reinterpret_cast<uint2*>(O2 + P - 2) = po;
        O3[P - 3] = po.x; O3[P - 2] = po.y;
        s4[64 * c + lane] =
            fmaf(v[c].x, v[c].x, fmaf(v[c].y, v[c].y, fmaf(v[c].z, v[c].z, v[c].w * v[c].w)));
    }
    if (lane < 8) {   // tail: zero pairs 512..527 into all 8 arrays (reads go to 523)
        const int P = 512 + 2 * lane;
        uint2 z = { 0u, 0u };
        *reinterpret_cast<uint2*>(E0 + P) = z;     // indices 512..527
        E1[P - 1] = 0u; E1[P] = 0u;                // 511..526
        *reinterpret_cast<uint2*>(E2 + P - 2) = z; // 510..525
        E3[P - 3] = 0u; E3[P - 2] = 0u;            // 509..524
        *reinterpret_cast<uint2*>(O0 + P) = z;
        O1[P - 1] = 0u; O1[P] = 0u;
        *reinterpret_cast<uint2*>(O2 + P - 2) = z;
        O3[P - 3] = 0u; O3[P - 2] = 0u;
    }
    if (lane < 8) s4[256 + lane] = 0.0f;

    // --- B fragments (fp16 RTZ) + exact fp32 ssq partials ---
    frag4 Bh[4];
    float ssq[4];
    #pragma unroll
    for (int lt = 0; lt < 4; ++lt) {
        const float* sp = shapelets + (lt * 16 + col) * KLEN + kg * 8;
        float4 f0 = *reinterpret_cast<const float4*>(sp);
        float4 f1 = *reinterpret_cast<const float4*>(sp + 4);
        Bh[lt].u[0] = pkh(f0.x, f0.y);
        Bh[lt].u[1] = pkh(f0.z, f0.w);
        Bh[lt].u[2] = pkh(f1.x, f1.y);
        Bh[lt].u[3] = pkh(f1.z, f1.w);
        float s = f0.x * f0.x;
        s = fmaf(f0.y, f0.y, s); s = fmaf(f0.z, f0.z, s); s = fmaf(f0.w, f0.w, s);
        s = fmaf(f1.x, f1.x, s); s = fmaf(f1.y, f1.y, s);
        s = fmaf(f1.z, f1.z, s); s = fmaf(f1.w, f1.w, s);
        ssq[lt] = s;   // kg-partial; reduced in epilogue
    }

    __builtin_amdgcn_wave_barrier();   // order pass-1 LDS writes before pass-2 reads

    // --- pass 2: win_sq from s4 partials + f16 sliding corrections -> nwh ---
    #pragma unroll
    for (int c = 0; c < 4; ++c) {
        const int q = 64 * c + lane;
        float s_[8];
        #pragma unroll
        for (int j = 0; j < 8; ++j) s_[j] = s4[q + j];
        float w0 = ((s_[0] + s_[1]) + (s_[2] + s_[3])) + ((s_[4] + s_[5]) + (s_[6] + s_[7]));
        uint32_t cw0 = E0[2 * (q + 8)];
        uint32_t cw1 = E0[2 * (q + 8) + 1];
        float x32 = lo16f(cw0), x33 = hi16f(cw0), x34 = lo16f(cw1);
        float w1 = fmaf(x32, x32, fmaf(-v[c].x, v[c].x, w0));
        float w2 = fmaf(x33, x33, fmaf(-v[c].y, v[c].y, w1));
        float w3 = fmaf(x34, x34, fmaf(-v[c].z, v[c].z, w2));
        const int p0 = 4 * q;
        float c0 = (p0 + 0 < NS) ? -0.5f * w0 : -60000.0f;
        float c1 = (p0 + 1 < NS) ? -0.5f * w1 : -60000.0f;
        float c2 = (p0 + 2 < NS) ? -0.5f * w2 : -60000.0f;
        float c3 = (p0 + 3 < NS) ? -0.5f * w3 : -60000.0f;
        const int qq = p0 & 31;
        const int W = ((p0 >> 5) << 4) + (((qq & 15) >> 2) << 2) + ((qq >> 4) << 1);
        uint2 hw = { pkh_rne(c0, c1), pkh_rne(c2, c3) };
        *reinterpret_cast<uint2*>(&nwh[W]) = hw;
    }

    __builtin_amdgcn_wave_barrier();   // order pass-2 stores before main-loop reads

    // --- main loop: 16 bodies x 2 tile-pairs; every A-fragment is a single
    //     aligned ds_read_b128 from the lane's shift-matched array. ---
    float rmax[4][4];
    #pragma unroll
    for (int lt = 0; lt < 4; ++lt)
        #pragma unroll
        for (int e = 0; e < 4; ++e) rmax[lt][e] = -3.0e38f;

    const int par = col & 1;
    const int cc  = col >> 1;
    const int r   = cc & 3;
    const int aoff = (par ? OFF_O0 : OFF_E0) + r * ASTRIDE;
    const uint4* fr  = reinterpret_cast<const uint4*>(lds + aoff + (cc + 4 * kg - r));
    const uint4* nwp = reinterpret_cast<const uint4*>(nwh);

    #pragma unroll 1
    for (int p = 0; p < 16; ++p) {
        frag4 Aa0, Ab0, Aa1, Ab1;
        Aa0.q = fr[8 * p + 0];
        Ab0.q = fr[8 * p + 2];
        Aa1.q = fr[8 * p + 4];
        Ab1.q = fr[8 * p + 6];
        uint4 nw0 = nwp[8 * p + kg];
        uint4 nw1 = nwp[8 * p + 4 + kg];

        f32x4 ia0, ib0, ia1, ib1;
        ia0[0] = lo16f(nw0.x); ia0[1] = hi16f(nw0.x);
        ia0[2] = lo16f(nw0.y); ia0[3] = hi16f(nw0.y);
        ib0[0] = lo16f(nw0.z); ib0[1] = hi16f(nw0.z);
        ib0[2] = lo16f(nw0.w); ib0[3] = hi16f(nw0.w);
        ia1[0] = lo16f(nw1.x); ia1[1] = hi16f(nw1.x);
        ia1[2] = lo16f(nw1.y); ia1[3] = hi16f(nw1.y);
        ib1[0] = lo16f(nw1.z); ib1[1] = hi16f(nw1.z);
        ib1[2] = lo16f(nw1.w); ib1[3] = hi16f(nw1.w);

        #pragma unroll
        for (int lt = 0; lt < 4; ++lt) {
            f32x4 aa0 = __builtin_amdgcn_mfma_f32_16x16x32_f16(Aa0.v, Bh[lt].v, ia0, 0, 0, 0);
            f32x4 ab0 = __builtin_amdgcn_mfma_f32_16x16x32_f16(Ab0.v, Bh[lt].v, ib0, 0, 0, 0);
            f32x4 aa1 = __builtin_amdgcn_mfma_f32_16x16x32_f16(Aa1.v, Bh[lt].v, ia1, 0, 0, 0);
            f32x4 ab1 = __builtin_amdgcn_mfma_f32_16x16x32_f16(Ab1.v, Bh[lt].v, ib1, 0, 0, 0);
            #pragma unroll
            for (int e = 0; e < 4; ++e) {
                rmax[lt][e] = fmaxf(fmaxf(aa0[e], ab0[e]), rmax[lt][e]);  // v_max3_f32
                rmax[lt][e] = fmaxf(fmaxf(aa1[e], ab1[e]), rmax[lt][e]);  // v_max3_f32
            }
        }
    }

    // --- epilogue: all in-wave shuffles, no LDS ---
    float p0v = 0.0f, p1v = 0.0f;
    #pragma unroll
    for (int lt = 0; lt < 4; ++lt) {
        float m = fmaxf(fmaxf(rmax[lt][0], rmax[lt][1]),
                        fmaxf(rmax[lt][2], rmax[lt][3]));
        m = fmaxf(m, __shfl_xor(m, 16, 64));
        m = fmaxf(m, __shfl_xor(m, 32, 64));
        float sq = ssq[lt];
        sq += __shfl_xor(sq, 16, 64);
        sq += __shfl_xor(sq, 32, 64);
        float f = (sq - 2.0f * m) * (1.0f / (float)KLEN);   // min dist
        p0v = fmaf(f, fc_w[lt * 16 + col], p0v);
        p1v = fmaf(f, fc_w[NL + lt * 16 + col], p1v);
    }
    #pragma unroll
    for (int off = 1; off <= 8; off <<= 1) {
        p0v += __shfl_xor(p0v, off, 64);
        p1v += __shfl_xor(p1v, off, 64);
    }
    if (lane == 0) {
        out[(size_t)row * 2 + 0] = p0v + fc_b[0];
        out[(size_t)row * 2 + 1] = p1v + fc_b[1];
    }
}

extern "C" void kernel_launch(void* const* d_in, const int* in_sizes, int n_in,
                              void* d_out, int out_size, void* d_ws, size_t ws_size,
                              hipStream_t stream) {
    const float* ts        = (const float*)d_in[0];
    const float* shapelets = (const float*)d_in[1];
    const float* fc_w      = (const float*)d_in[2];
    const float* fc_b      = (const float*)d_in[3];
    float* out = (float*)d_out;

    shapelet_r19<<<NB, 64, 0, stream>>>(ts, shapelets, fc_w, fc_b, out);
}